// Round 1
// 302.774 us; speedup vs baseline: 1.0453x; 1.0453x over previous
//
#include <hip/hip_runtime.h>

// GLIFR RNN (B=64, T=200, IN=512, HID=1024, OUT=512), fp32 in/out, bf16 MFMA.
//
// DELAY=20 decouples the lateral matmul -> 10 chunks of 20 steps.
//
// Round 4: fused per-chunk kernel. M-tile = 80 rows (20 t x 4 b) x 64 h so a
// single block owns the whole chunk for its (b,h) tile: lateral GEMM
// (init from x_proj) -> acc spilled to LDS -> 20-step GLIFR recurrence
// in-block (1 (b,h) pair per thread). Eliminates the syn write+re-read
// round-trip (94 MB over 9 chunks) and halves the serialized dispatch count.
// syn[] now holds x_proj only and is read-only after the input projection.
//
// Workspace (~84 MB):
//   syn   fp32 [T,B,H]  @ 0          (52428800 B)  x_proj (read-only after GEMM)
//   state fp32 4x[B*H]  @ 52428800   (1048576 B)   volt, asc0, asc1, firing
//   F     bf16 [T,B,H]  @ 53477376   (26214400 B)  firing history
//     xb  bf16 [12800,512] overlays F (dead before first F write)
//   WinT  bf16 [H,IN]   @ 79691776   (1048576 B)
//   WlatT bf16 [H,H]    @ 80740352   (2097152 B)
//   WoutB bf16 [OUT,H]  @ 82837504   (1048576 B)

typedef float f32x4 __attribute__((ext_vector_type(4)));
typedef __bf16 bf16x8 __attribute__((ext_vector_type(8)));
typedef unsigned short ushortx8 __attribute__((ext_vector_type(8)));
typedef unsigned short ushortx4 __attribute__((ext_vector_type(4)));

__device__ __forceinline__ unsigned short f2b(float f) {
    unsigned int u = __float_as_uint(f);
    unsigned int r = u + 0x7FFFu + ((u >> 16) & 1u);   // RNE
    return (unsigned short)(r >> 16);
}
__device__ __forceinline__ float sigmoidf(float x) {
    return 1.0f / (1.0f + __expf(-x));
}

// async global->LDS, 16 B per lane; lptr must be wave-uniform (HW adds lane*16)
__device__ __forceinline__ void gl_lds16(const unsigned short* g, unsigned short* l) {
    __builtin_amdgcn_global_load_lds(
        (const __attribute__((address_space(1))) void*)g,
        (__attribute__((address_space(3))) void*)l, 16, 0, 0);
}

// ---------------------------------------------------------------------------
// fp32 [R,C] -> bf16 transposed [C,R]
// ---------------------------------------------------------------------------
__global__ __launch_bounds__(256) void transpose_f32_to_bf16(
    const float* __restrict__ in, unsigned short* __restrict__ out,
    int R, int C)
{
    __shared__ unsigned short t[64][65];
    int bx = blockIdx.x * 64, by = blockIdx.y * 64;
    int tx = threadIdx.x & 63, ty = threadIdx.x >> 6;
    for (int r = ty; r < 64; r += 4)
        t[r][tx] = f2b(in[(size_t)(by + r) * C + bx + tx]);
    __syncthreads();
    for (int r = ty; r < 64; r += 4)
        out[(size_t)(bx + r) * R + by + tx] = t[tx][r];
}

// fp32 -> bf16 elementwise (n multiple of 1024)
__global__ __launch_bounds__(256) void convert_f32_to_bf16(
    const float* __restrict__ in, unsigned short* __restrict__ out)
{
    int i = (blockIdx.x * 256 + threadIdx.x) * 4;
    f32x4 v = *(const f32x4*)(in + i);
    ushortx4 o;
    o[0] = f2b(v[0]); o[1] = f2b(v[1]); o[2] = f2b(v[2]); o[3] = f2b(v[3]);
    *(ushortx4*)(out + i) = o;
}

// x [B=64,T=200,IN=512] fp32 -> xb [m=t*64+b][512] bf16
__global__ __launch_bounds__(256) void convert_x(
    const float* __restrict__ x, unsigned short* __restrict__ xb)
{
    size_t i8 = (size_t)(blockIdx.x * 256 + threadIdx.x) * 8;   // grid 3200
    int m = (int)(i8 >> 9), k = (int)(i8 & 511);
    int b = m & 63, t = m >> 6;
    const float* src = x + ((size_t)b * 200 + t) * 512 + k;
    f32x4 v0 = *(const f32x4*)src;
    f32x4 v1 = *(const f32x4*)(src + 4);
    ushortx8 o;
    o[0] = f2b(v0[0]); o[1] = f2b(v0[1]); o[2] = f2b(v0[2]); o[3] = f2b(v0[3]);
    o[4] = f2b(v1[0]); o[5] = f2b(v1[1]); o[6] = f2b(v1[2]); o[7] = f2b(v1[3]);
    *(ushortx8*)(xb + i8) = o;
}

// ---------------------------------------------------------------------------
// NT GEMM: C[m,n] = sum_k A[m,k] * Bt[n,k]; A,Bt bf16 row-major K-contig.
// LDS layout (per tile row, 128 B = 8 slots of 16 B): element chunk c of row r
// lives at slot (c ^ (r&7)) -> conflict-free ds_read_b128 fragments with the
// unpadded layout global_load_lds requires.
// MODE 0: zero init, fp32 out identity rows.            (input projection)
// MODE 2: zero init, +bias, fp32 out remapped [B,T,OUT] (readout)
// Block = 256 threads, 4 waves 2x2; wave tile (BM/2)x(BN/2); MFMA 16x16x32.
// ---------------------------------------------------------------------------
template<int BM, int BN, int MODE>
__global__ __launch_bounds__(256) void gemm_nt(
    const unsigned short* __restrict__ A,
    const unsigned short* __restrict__ Bt,
    float* __restrict__ outf,
    const float* __restrict__ bias,
    int M, int N, int K)
{
    constexpr int WM = BM / 2, WN = BN / 2;
    constexpr int TM = WM / 16, TN = WN / 16;

    __shared__ unsigned short Asm[BM * 64];
    __shared__ unsigned short Bsm[BN * 64];

    const int tid  = threadIdx.x;
    const int wave = tid >> 6, lane = tid & 63;
    const int m16  = lane & 15, quad = lane >> 4;
    const int bm0  = blockIdx.y * BM, bn0 = blockIdx.x * BN;
    const int wr   = (wave >> 1) * WM, wc = (wave & 1) * WN;
    const int sr   = lane >> 3;        // row within an 8-row staging group
    const int sc   = lane & 7;         // LDS 16B slot within the row

    f32x4 acc[TM][TN];
#pragma unroll
    for (int i = 0; i < TM; i++)
#pragma unroll
        for (int j = 0; j < TN; j++)
            acc[i][j] = (f32x4){0.f, 0.f, 0.f, 0.f};

    for (int k0 = 0; k0 < K; k0 += 64) {
        // async staging: each wave-instr fills 8 rows (1024 B) of LDS
#pragma unroll
        for (int g = wave; g < BM / 8; g += 4) {
            int r = g * 8 + sr;
            int c = sc ^ (r & 7);                       // global-side swizzle
            gl_lds16(A + (size_t)(bm0 + r) * K + k0 + c * 8, Asm + g * 512);
        }
#pragma unroll
        for (int g = wave; g < BN / 8; g += 4) {
            int r = g * 8 + sr;
            int c = sc ^ (r & 7);
            gl_lds16(Bt + (size_t)(bn0 + r) * K + k0 + c * 8, Bsm + g * 512);
        }
        __syncthreads();

        ushortx8 af[2][TM], bfr[2][TN];
#pragma unroll
        for (int kh = 0; kh < 2; kh++) {
#pragma unroll
            for (int i = 0; i < TM; i++) {
                int ra = wr + i * 16 + m16;
                af[kh][i] = *(const ushortx8*)(
                    Asm + ra * 64 + (((kh * 4 + quad) ^ (ra & 7)) * 8));
            }
#pragma unroll
            for (int j = 0; j < TN; j++) {
                int rb = wc + j * 16 + m16;
                bfr[kh][j] = *(const ushortx8*)(
                    Bsm + rb * 64 + (((kh * 4 + quad) ^ (rb & 7)) * 8));
            }
        }
#pragma unroll
        for (int i = 0; i < TM; i++)
#pragma unroll
            for (int j = 0; j < TN; j++) {
                acc[i][j] = __builtin_amdgcn_mfma_f32_16x16x32_bf16(
                    __builtin_bit_cast(bf16x8, af[0][i]),
                    __builtin_bit_cast(bf16x8, bfr[0][j]),
                    acc[i][j], 0, 0, 0);
                acc[i][j] = __builtin_amdgcn_mfma_f32_16x16x32_bf16(
                    __builtin_bit_cast(bf16x8, af[1][i]),
                    __builtin_bit_cast(bf16x8, bfr[1][j]),
                    acc[i][j], 0, 0, 0);
            }
        __syncthreads();
    }

    // epilogue; C/D layout: col = lane&15, row = quad*4 + reg  (m89-verified)
#pragma unroll
    for (int i = 0; i < TM; i++)
#pragma unroll
        for (int j = 0; j < TN; j++) {
            int col = bn0 + wc + j * 16 + m16;
            float bv = (MODE == 2) ? bias[col] : 0.f;
#pragma unroll
            for (int v = 0; v < 4; v++) {
                int row = bm0 + wr + i * 16 + quad * 4 + v;
                if (MODE == 2) {
                    // m = t*64+b  ->  out[(b*200+t)*N + col]
                    size_t o = (size_t)((row & 63) * 200 + (row >> 6)) * N + col;
                    outf[o] = acc[i][j][v] + bv;
                } else {
                    outf[(size_t)row * N + col] = acc[i][j][v];
                }
            }
        }
}

// ---------------------------------------------------------------------------
// Fused lateral GEMM + 20-step GLIFR recurrence for one chunk (c >= 1).
// Block tile: M = 80 rows (20 t x 4 b, row r <-> t=r>>2, b=b0+(r&3)), N = 64 h.
// Grid (16 h-tiles, 16 b-tiles) = 256 blocks, 256 threads (4 waves).
// Uneven 2x2 wave split: waves 0,1 rows 0..47 (TM=3); waves 2,3 rows 48..79
// (TM=2); N halves of 32 (TN=2) -> 40 MFMA : 36 ds_read_b128 per k64-step.
// After the K-loop, acc (= syn tile, init'd from x_proj) is spilled to LDS
// (overlaying the staging buffers) and each thread runs the 20-step
// recurrence for one (b,h) pair: b = wave, h = lane.
// ---------------------------------------------------------------------------
__global__ __launch_bounds__(256) void fused_chunk(
    const unsigned short* __restrict__ Fprev, // [1280,1024] bf16, rows t*64+b
    const unsigned short* __restrict__ Wlat,  // [1024,1024] bf16 NT
    const float* __restrict__ xproj,          // [1280,1024] fp32 (syn chunk c)
    float* __restrict__ state,                // 4 x [B*H]
    unsigned short* __restrict__ Fc,          // F chunk c out
    const float* __restrict__ thresh,
    const float* __restrict__ t_km,
    const float* __restrict__ t_ak,
    const float* __restrict__ amp,
    const float* __restrict__ t_ar)
{
    const int BH = 64 * 1024;
    __shared__ __align__(16) char lds[21120];
    unsigned short* Asm = (unsigned short*)lds;            // 80*64 us = 10240 B
    unsigned short* Bsm = (unsigned short*)(lds + 10240);  // 64*64 us =  8192 B
    float* synT = (float*)lds;                             // 80*66 f32 = 21120 B

    const int tid  = threadIdx.x;
    const int wave = tid >> 6, lane = tid & 63;
    const int m16  = lane & 15, quad = lane >> 4;
    const int sr   = lane >> 3, sc = lane & 7;
    const int b0   = blockIdx.y * 4, h0 = blockIdx.x * 64;
    const int wrow = (wave >> 1) * 48;
    const int wc   = (wave & 1) * 32;

    f32x4 acc[3][2];
    // acc init = x_proj tile (syn is read-only now)
#pragma unroll
    for (int i = 0; i < 3; i++) {
        if (i < 2 || wave < 2) {
#pragma unroll
            for (int j = 0; j < 2; j++)
#pragma unroll
                for (int v = 0; v < 4; v++) {
                    int row = wrow + i * 16 + quad * 4 + v;
                    int col = h0 + wc + j * 16 + m16;
                    acc[i][j][v] = xproj[(size_t)(((row >> 2) << 6) + b0 + (row & 3)) * 1024 + col];
                }
        }
    }

    for (int k0 = 0; k0 < 1024; k0 += 64) {
        // A: F rows m = t*64 + b0 + b_local, 10 groups of 8 LDS rows
        for (int g = wave; g < 10; g += 4) {
            int r = g * 8 + sr;
            int c = sc ^ (r & 7);
            int m = ((r >> 2) << 6) + b0 + (r & 3);
            gl_lds16(Fprev + (size_t)m * 1024 + k0 + c * 8, Asm + g * 512);
        }
        // B: Wlat rows h0+r, 8 groups
        for (int g = wave; g < 8; g += 4) {
            int r = g * 8 + sr;
            int c = sc ^ (r & 7);
            gl_lds16(Wlat + (size_t)(h0 + r) * 1024 + k0 + c * 8, Bsm + g * 512);
        }
        __syncthreads();

        ushortx8 af[2][3], bfr[2][2];
#pragma unroll
        for (int kh = 0; kh < 2; kh++) {
#pragma unroll
            for (int i = 0; i < 3; i++) {
                if (i < 2 || wave < 2) {
                    int ra = wrow + i * 16 + m16;
                    af[kh][i] = *(const ushortx8*)(
                        Asm + ra * 64 + (((kh * 4 + quad) ^ (ra & 7)) * 8));
                }
            }
#pragma unroll
            for (int j = 0; j < 2; j++) {
                int rb = wc + j * 16 + m16;
                bfr[kh][j] = *(const ushortx8*)(
                    Bsm + rb * 64 + (((kh * 4 + quad) ^ (rb & 7)) * 8));
            }
        }
#pragma unroll
        for (int i = 0; i < 3; i++) {
            if (i < 2 || wave < 2) {
#pragma unroll
                for (int j = 0; j < 2; j++) {
                    acc[i][j] = __builtin_amdgcn_mfma_f32_16x16x32_bf16(
                        __builtin_bit_cast(bf16x8, af[0][i]),
                        __builtin_bit_cast(bf16x8, bfr[0][j]), acc[i][j], 0, 0, 0);
                    acc[i][j] = __builtin_amdgcn_mfma_f32_16x16x32_bf16(
                        __builtin_bit_cast(bf16x8, af[1][i]),
                        __builtin_bit_cast(bf16x8, bfr[1][j]), acc[i][j], 0, 0, 0);
                }
            }
        }
        __syncthreads();
    }

    // spill syn tile to LDS (overlays staging buffers; safe after barrier).
    // stride 66 words: quads land 8 banks apart -> 2-way (free) on write+read.
#pragma unroll
    for (int i = 0; i < 3; i++) {
        if (i < 2 || wave < 2) {
#pragma unroll
            for (int j = 0; j < 2; j++)
#pragma unroll
                for (int v = 0; v < 4; v++) {
                    int row = wrow + i * 16 + quad * 4 + v;
                    synT[row * 66 + wc + j * 16 + m16] = acc[i][j][v];
                }
        }
    }
    __syncthreads();

    // 20-step recurrence: thread -> (b = wave, h = lane)
    const int h    = h0 + lane;
    const int gidx = (b0 + wave) * 1024 + h;
    float th  = thresh[h];
    float sm  = sigmoidf(t_km[h]);             // DT*k_m
    float rm  = 0.1f * sm;                     // R_MEM*DT*k_m
    float om  = 1.0f - sm;
    float sa0 = sigmoidf(t_ak[h]);
    float sa1 = sigmoidf(t_ak[1024 + h]);
    float am0 = amp[h];
    float am1 = amp[1024 + h];
    float r0  = 1.0f - 2.0f * sigmoidf(t_ar[h]);
    float r1  = 1.0f - 2.0f * sigmoidf(t_ar[1024 + h]);

    float volt = state[gidx];
    float a0   = state[BH + gidx];
    float a1   = state[2 * BH + gidx];
    float fir  = state[3 * BH + gidx];

#pragma unroll
    for (int s = 0; s < 20; s++) {
        float sv  = synT[(s * 4 + wave) * 66 + lane];
        float na0 = (am0 + r0 * a0) * fir * sa0 + (1.f - sa0) * a0;
        float na1 = (am1 + r1 * a1) * fir * sa1 + (1.f - sa1) * a1;
        volt = rm * (sv + na0 + na1) + om * volt;
        fir  = sigmoidf(volt - th);
        Fc[(size_t)s * BH + gidx] = f2b(fir);
        a0 = na0; a1 = na1;
    }
    state[gidx]          = volt;
    state[BH + gidx]     = a0;
    state[2 * BH + gidx] = a1;
    state[3 * BH + gidx] = fir;
}

// ---------------------------------------------------------------------------
// GLIFR elementwise recurrence for chunk 0 (zero initial state, syn = x_proj).
// ---------------------------------------------------------------------------
__global__ __launch_bounds__(256) void chunk_step(
    const float* __restrict__ syn,       // [T,B,H] fp32
    float* __restrict__ state,           // 4 x [B*H]: volt, asc0, asc1, firing
    unsigned short* __restrict__ F,      // [T,B,H] bf16
    const float* __restrict__ thresh,
    const float* __restrict__ t_km,
    const float* __restrict__ t_ak,      // [2,H]
    const float* __restrict__ amp,       // [2,H]
    const float* __restrict__ t_ar)      // [2,H]
{
    const int BH = 64 * 1024;
    int idx = blockIdx.x * 256 + threadIdx.x;   // b*1024 + h
    int h = idx & 1023;

    float th  = thresh[h];
    float sm  = sigmoidf(t_km[h]);             // DT*k_m
    float rm  = 0.1f * sm;                     // R_MEM*DT*k_m
    float om  = 1.0f - sm;
    float sa0 = sigmoidf(t_ak[h]);
    float sa1 = sigmoidf(t_ak[1024 + h]);
    float am0 = amp[h];
    float am1 = amp[1024 + h];
    float r0  = 1.0f - 2.0f * sigmoidf(t_ar[h]);
    float r1  = 1.0f - 2.0f * sigmoidf(t_ar[1024 + h]);

    float volt = 0.f, a0 = 0.f, a1 = 0.f, fir = 0.f;

#pragma unroll
    for (int s = 0; s < 20; s++) {
        float sv  = syn[(size_t)s * BH + idx];
        float na0 = (am0 + r0 * a0) * fir * sa0 + (1.f - sa0) * a0;
        float na1 = (am1 + r1 * a1) * fir * sa1 + (1.f - sa1) * a1;
        volt = rm * (sv + na0 + na1) + om * volt;
        fir  = sigmoidf(volt - th);
        F[(size_t)s * BH + idx] = f2b(fir);
        a0 = na0; a1 = na1;
    }
    state[idx]          = volt;
    state[BH + idx]     = a0;
    state[2 * BH + idx] = a1;
    state[3 * BH + idx] = fir;
}

// ---------------------------------------------------------------------------
extern "C" void kernel_launch(void* const* d_in, const int* in_sizes, int n_in,
                              void* d_out, int out_size, void* d_ws, size_t ws_size,
                              hipStream_t stream)
{
    const float* x      = (const float*)d_in[0];  // [64,200,512]
    const float* W_in   = (const float*)d_in[1];  // [512,1024]
    const float* W_lat  = (const float*)d_in[2];  // [1024,1024]
    const float* thresh = (const float*)d_in[3];  // [1,1024]
    const float* t_km   = (const float*)d_in[4];  // [1,1024]
    const float* t_ak   = (const float*)d_in[5];  // [2,1,1024]
    const float* amp    = (const float*)d_in[6];  // [2,1,1024]
    const float* t_ar   = (const float*)d_in[7];  // [2,1,1024]
    const float* W_out  = (const float*)d_in[8];  // [512,1024] (n,k) already!
    const float* b_out  = (const float*)d_in[9];  // [512]
    float* out = (float*)d_out;                   // [64,200,512]

    char* ws = (char*)d_ws;
    float*          syn   = (float*)ws;                     // [T,B,H] fp32 x_proj
    float*          state = (float*)(ws + 52428800);
    unsigned short* F     = (unsigned short*)(ws + 53477376);
    unsigned short* xb    = F;  // overlay: dead before first F write
    unsigned short* WinT  = (unsigned short*)(ws + 79691776);
    unsigned short* WlatT = (unsigned short*)(ws + 80740352);
    unsigned short* WoutB = (unsigned short*)(ws + 82837504);

    // Prep: transpose/convert weights to bf16 NT layout; x to bf16 m-order.
    transpose_f32_to_bf16<<<dim3(16, 8),  256, 0, stream>>>(W_in,  WinT,  512,  1024);
    transpose_f32_to_bf16<<<dim3(16, 16), 256, 0, stream>>>(W_lat, WlatT, 1024, 1024);
    convert_f32_to_bf16<<<512, 256, 0, stream>>>(W_out, WoutB);  // [512,1024] is (n,k)
    convert_x<<<3200, 256, 0, stream>>>(x, xb);

    // x_proj (= syn, read-only from here on): [12800,1024] = xb @ WinT^T
    gemm_nt<128, 128, 0><<<dim3(1024 / 128, 12800 / 128), 256, 0, stream>>>(
        xb, WinT, syn, nullptr, 12800, 1024, 512);

    // chunk 0: no lateral term, zero initial state
    chunk_step<<<256, 256, 0, stream>>>(syn, state, F, thresh, t_km, t_ak, amp, t_ar);

    const size_t CHUNK = 20 * 64 * 1024;  // elements per chunk of [T,B,H]
    for (int c = 1; c < 10; c++) {
        fused_chunk<<<dim3(16, 16), 256, 0, stream>>>(
            F + (size_t)(c - 1) * CHUNK, WlatT,
            syn + (size_t)c * CHUNK, state, F + (size_t)c * CHUNK,
            thresh, t_km, t_ak, amp, t_ar);
    }

    // readout: out[b,t,:] = F[t,b,:] @ W_out^T + b_out  (W_out already [n,k])
    gemm_nt<128, 128, 2><<<dim3(512 / 128, 12800 / 128), 256, 0, stream>>>(
        F, WoutB, out, b_out, 12800, 512, 1024);
}